// Round 7
// baseline (225.396 us; speedup 1.0000x reference)
//
#include <hip/hip_runtime.h>

typedef _Float16 half8 __attribute__((ext_vector_type(8)));
typedef _Float16 half4 __attribute__((ext_vector_type(4)));
typedef float f32x4 __attribute__((ext_vector_type(4)));

#define TT 512
#define HH 64
#define MB 4      // batches/block -> 512 blocks -> 2 INDEPENDENT blocks/CU (antiphase)
#define S  88     // state row stride (halfs): writes bank-bijective, reads 2-way (free)
#define XS 4112   // xbuf per-batch stride (halfs): 514*8 -> pad absorbs t+2 prefetch

__global__ __launch_bounds__(256, 2)
void lstm_v18(const float* __restrict__ x,
              const float* __restrict__ W_ih,
              const float* __restrict__ W_hh,
              const float* __restrict__ b_ih,
              const float* __restrict__ b_hh,
              const float* __restrict__ W_fc,
              const float* __restrict__ b_fc,
              float* __restrict__ out)
{
    __shared__ __align__(16) _Float16 st[2][MB * S];     // 1408 B: h state, dbuf
    __shared__ __align__(16) _Float16 xbuf[MB * XS];     // 32896 B: pre-packed x B-frags

    const int tid = threadIdx.x;
    const int w   = tid >> 6;      // wave 0..3
    const int l   = tid & 63;
    const int q   = l >> 4;
    const int col = l & 15;
    const int bt  = col & 3;       // batch within block (4 replica col-groups in MFMA only)
    const int g   = col >> 2;      // tile selector: lane owns unit 16w+4g+q, batch bt
    const int b0  = blockIdx.x * MB;

    const float kN = -1.4426950408889634f;   // -log2(e)
    const float kP =  2.8853900817779268f;   // +2*log2(e)

    // ---- persistent A fragments: 4 tiles/wave, tile p covers units 16w+4p+q ----
    // tile p, C-row m: gate-row r(m) = 64*(m&3) + 16w + 4p + (m>>2)
    // => C: lane (q,col) reg j = gate j of unit 16w+4p+q  (batch col&3)  [v13-verified]
    // Weights PRESCALED by exp2 constants (f32 mul BEFORE f16 cvt: single rounding).
    half8 aw[4][3];
    #pragma unroll
    for (int p = 0; p < 4; ++p) {
        const int r = 64 * (col & 3) + 16 * w + 4 * p + (col >> 2);
        const float scale = ((col & 3) == 2) ? kP : kN;   // gate g -> kP, i/f/o -> kN
        #pragma unroll
        for (int c = 0; c < 2; ++c) {
            const float* src = W_hh + r * HH + 32 * c + 8 * q;
            half8 v;
            #pragma unroll
            for (int j = 0; j < 8; ++j) v[j] = (_Float16)(src[j] * scale);
            aw[p][c] = v;
        }
        half8 v = {};
        if (q == 0) {   // k=64..67 -> W_ih, k=68 -> bias (B supplies 1.0 at k=68)
            #pragma unroll
            for (int j = 0; j < 4; ++j) v[j] = (_Float16)(W_ih[r * 4 + j] * scale);
            v[4] = (_Float16)((b_ih[r] + b_hh[r]) * scale);
        }
        aw[p][2] = v;
    }

    // ---- pre-stage x as ready-to-use B-frags: {x0,x1,x2,x3,1,0,0,0} per (b,t) ----
    #pragma unroll
    for (int it = 0; it < (MB * TT) / 256; ++it) {
        const int task = tid + it * 256;
        const int b = task >> 9, t = task & 511;
        float4 v = *(const float4*)(x + ((size_t)(b0 + b) * TT + t) * 4);
        half8 hx;
        hx[0] = (_Float16)v.x; hx[1] = (_Float16)v.y;
        hx[2] = (_Float16)v.z; hx[3] = (_Float16)v.w;
        hx[4] = (_Float16)1.0f; hx[5] = (_Float16)0.f;
        hx[6] = (_Float16)0.f;  hx[7] = (_Float16)0.f;
        *(half8*)&xbuf[b * XS + t * 8] = hx;
    }

    // ---- zero h state (both buffers) ----
    for (int i = tid; i < 2 * MB * S; i += 256) (&st[0][0])[i] = (_Float16)0.f;
    __syncthreads();

    float cs2 = 0.f;               // carried state = kP * c (folds the EC multiply)
    const int wrow = bt * S + 16 * w + 4 * g + q;   // write addr: bank-bijective per wave
    const f32x4 z4 = {0.f, 0.f, 0.f, 0.f};
    const bool sA = (col & 4) != 0, sB = (col & 8) != 0;

    // x-pipeline: accx[p] = x-contribution for step t (ready); bxn = B-frag for t+1
    f32x4 accx0, accx1, accx2, accx3;
    half8 bxn;
    {
        half8 bx0 = *(const half8*)&xbuf[bt * XS + 0];
        accx0 = __builtin_amdgcn_mfma_f32_16x16x32_f16(aw[0][2], bx0, z4, 0, 0, 0);
        accx1 = __builtin_amdgcn_mfma_f32_16x16x32_f16(aw[1][2], bx0, z4, 0, 0, 0);
        accx2 = __builtin_amdgcn_mfma_f32_16x16x32_f16(aw[2][2], bx0, z4, 0, 0, 0);
        accx3 = __builtin_amdgcn_mfma_f32_16x16x32_f16(aw[3][2], bx0, z4, 0, 0, 0);
        bxn = *(const half8*)&xbuf[bt * XS + 8];
    }

    #pragma unroll 2
    for (int t = 0; t < TT; ++t) {
        const int rb = t & 1, wb = rb ^ 1;
        const _Float16* sr = &st[rb][0];

        // ---- critical reads first (2-way banks max: free) ----
        half8 bh0 = *(const half8*)&sr[bt * S +      8 * q];   // k 0..31
        half8 bh1 = *(const half8*)&sr[bt * S + 32 + 8 * q];   // k 32..63

        // ---- x-MFMAs for t+1: operands in regs -> issue inside read latency ----
        f32x4 axn0 = __builtin_amdgcn_mfma_f32_16x16x32_f16(aw[0][2], bxn, z4, 0, 0, 0);
        f32x4 axn1 = __builtin_amdgcn_mfma_f32_16x16x32_f16(aw[1][2], bxn, z4, 0, 0, 0);
        f32x4 axn2 = __builtin_amdgcn_mfma_f32_16x16x32_f16(aw[2][2], bxn, z4, 0, 0, 0);
        f32x4 axn3 = __builtin_amdgcn_mfma_f32_16x16x32_f16(aw[3][2], bxn, z4, 0, 0, 0);

        bxn = *(const half8*)&xbuf[bt * XS + (t + 2) * 8];     // prefetch (pad-safe)

        // ---- h-MFMAs: 4 independent chains of depth 2 ----
        f32x4 a0 = __builtin_amdgcn_mfma_f32_16x16x32_f16(aw[0][0], bh0, accx0, 0, 0, 0);
        f32x4 a1 = __builtin_amdgcn_mfma_f32_16x16x32_f16(aw[1][0], bh0, accx1, 0, 0, 0);
        f32x4 a2 = __builtin_amdgcn_mfma_f32_16x16x32_f16(aw[2][0], bh0, accx2, 0, 0, 0);
        f32x4 a3 = __builtin_amdgcn_mfma_f32_16x16x32_f16(aw[3][0], bh0, accx3, 0, 0, 0);
        a0 = __builtin_amdgcn_mfma_f32_16x16x32_f16(aw[0][1], bh1, a0, 0, 0, 0);
        a1 = __builtin_amdgcn_mfma_f32_16x16x32_f16(aw[1][1], bh1, a1, 0, 0, 0);
        a2 = __builtin_amdgcn_mfma_f32_16x16x32_f16(aw[2][1], bh1, a2, 0, 0, 0);
        a3 = __builtin_amdgcn_mfma_f32_16x16x32_f16(aw[3][1], bh1, a3, 0, 0, 0);

        // ---- select this lane's unit: acc[col>>2] (12 cndmask, all in-lane) ----
        #define SEL(j) (sB ? (sA ? a3[j] : a2[j]) : (sA ? a1[j] : a0[j]))
        const float gi = SEL(0);   // prescaled by kN
        const float gf = SEL(1);   // prescaled by kN
        const float gg = SEL(2);   // prescaled by kP
        const float go = SEL(3);   // prescaled by kN
        #undef SEL

        const float EI = __builtin_amdgcn_exp2f(gi);
        const float EF = __builtin_amdgcn_exp2f(gf);
        const float EG = __builtin_amdgcn_exp2f(gg);
        const float rF = __builtin_amdgcn_rcpf(1.f + EF);
        const float r1 = __builtin_amdgcn_rcpf((1.f + EI) * (EG + 1.f));
        const float Y  = (kP * (EG - 1.f)) * r1;      // kP folded off-chain
        cs2 = cs2 * rF + Y;                           // cs2 == kP * c
        const float EO = __builtin_amdgcn_exp2f(go);
        const float EC = __builtin_amdgcn_exp2f(cs2);
        const float r2 = __builtin_amdgcn_rcpf((1.f + EO) * (EC + 1.f));
        const float hn = (EC - 1.f) * r2;

        st[wb][wrow] = (_Float16)hn;    // all 64 lanes write: bank-bijective, conflict-free
        __syncthreads();

        accx0 = axn0; accx1 = axn1; accx2 = axn2; accx3 = axn3;
    }

    // ---- FC epilogue: final h in st[0] (TT even) ----
    if (tid < MB * 4) {
        const int b = tid >> 2, o = tid & 3;
        float s = b_fc[o];
        const float* wf = W_fc + o * HH;
        #pragma unroll
        for (int k = 0; k < HH; ++k)
            s = fmaf((float)st[0][b * S + k], wf[k], s);
        out[(size_t)(b0 + b) * 4 + o] = s;
    }
}

extern "C" void kernel_launch(void* const* d_in, const int* in_sizes, int n_in,
                              void* d_out, int out_size, void* d_ws, size_t ws_size,
                              hipStream_t stream) {
    const float* x    = (const float*)d_in[0];
    const float* W_ih = (const float*)d_in[1];
    const float* W_hh = (const float*)d_in[2];
    const float* b_ih = (const float*)d_in[3];
    const float* b_hh = (const float*)d_in[4];
    const float* W_fc = (const float*)d_in[5];
    const float* b_fc = (const float*)d_in[6];
    float* out = (float*)d_out;
    lstm_v18<<<2048 / MB, 256, 0, stream>>>(x, W_ih, W_hh, b_ih, b_hh, W_fc, b_fc, out);
}

// Round 8
// 214.473 us; speedup vs baseline: 1.0509x; 1.0509x over previous
//
#include <hip/hip_runtime.h>

typedef _Float16 half8 __attribute__((ext_vector_type(8)));
typedef _Float16 half4 __attribute__((ext_vector_type(4)));
typedef float f32x4 __attribute__((ext_vector_type(4)));

#define TT 512
#define HH 64
#define MB 8      // real batches per block -> 256 blocks; cols 8..15 are broadcast dups
#define S  88     // state row stride (halfs): h-writes bank-bijective, reads at BW floor
#define XS 4112   // xbuf per-batch stride (halfs): 514*8 -> pad absorbs t+2 prefetch

__global__ __launch_bounds__(512, 1)
void lstm_v19(const float* __restrict__ x,
              const float* __restrict__ W_ih,
              const float* __restrict__ W_hh,
              const float* __restrict__ b_ih,
              const float* __restrict__ b_hh,
              const float* __restrict__ W_fc,
              const float* __restrict__ b_fc,
              float* __restrict__ out)
{
    __shared__ __align__(16) _Float16 st[2][8 * S];      // 2816 B: h state, dbuf
    __shared__ __align__(16) _Float16 xbuf[MB * XS];     // 65792 B: pre-packed x B-frags

    const int tid = threadIdx.x;
    const int w   = tid >> 6;      // wave 0..7
    const int l   = tid & 63;
    const int q   = l >> 4;
    const int col = l & 15;
    const int b0  = blockIdx.x * MB;
    const int xcol = col & 7;      // cols 8..15 broadcast a real batch
    const bool lo = (col < 8);

    const float kN = -1.4426950408889634f;   // -log2(e)
    const float kP =  2.8853900817779268f;   // +2*log2(e)

    // ---- persistent A fragments (weights), 2 tiles per wave ----
    // tile p of wave w covers gate-rows r(m) = 64*(m&3) + 8w + 2*(m>>2) + p
    // => lane (q,col) reg j = gate j of unit u = 8w + 2q + p  (batch col&7)
    //    NOTE: C value is independent of col-half; cols>=8 already hold the
    //    p=1 result for batch col-8 locally -> NO cross-lane redistribution.
    // Weights PRESCALED by the sigmoid/tanh exp2 constants (f32 mul BEFORE f16
    // convert: same single rounding as unscaled).
    half8 aw[2][3];
    #pragma unroll
    for (int p = 0; p < 2; ++p) {
        const int r = 64 * (col & 3) + 8 * w + 2 * (col >> 2) + p;
        const float scale = ((col & 3) == 2) ? kP : kN;   // gate g -> kP, i/f/o -> kN
        #pragma unroll
        for (int c = 0; c < 2; ++c) {
            const float* src = W_hh + r * HH + 32 * c + 8 * q;
            half8 v;
            #pragma unroll
            for (int j = 0; j < 8; ++j) v[j] = (_Float16)(src[j] * scale);
            aw[p][c] = v;
        }
        half8 v = {};
        if (q == 0) {   // k=64..67 -> W_ih, k=68 -> bias (B supplies 1.0 at k=68)
            #pragma unroll
            for (int j = 0; j < 4; ++j) v[j] = (_Float16)(W_ih[r * 4 + j] * scale);
            v[4] = (_Float16)((b_ih[r] + b_hh[r]) * scale);
        }
        aw[p][2] = v;
    }

    // ---- pre-stage x as ready-to-use B-frags: {x0,x1,x2,x3,1,0,0,0} per (b,t) ----
    #pragma unroll
    for (int it = 0; it < (MB * TT) / 512; ++it) {
        const int task = tid + it * 512;
        const int b = task >> 9, t = task & 511;
        float4 v = *(const float4*)(x + ((size_t)(b0 + b) * TT + t) * 4);
        half8 hx;
        hx[0] = (_Float16)v.x; hx[1] = (_Float16)v.y;
        hx[2] = (_Float16)v.z; hx[3] = (_Float16)v.w;
        hx[4] = (_Float16)1.0f; hx[5] = (_Float16)0.f;
        hx[6] = (_Float16)0.f;  hx[7] = (_Float16)0.f;
        *(half8*)&xbuf[b * XS + t * 8] = hx;
    }

    // ---- zero h state (both buffers, all 8 rows) ----
    for (int i = tid; i < 2 * 8 * S; i += 512) (&st[0][0])[i] = (_Float16)0.f;
    __syncthreads();

    float cs2 = 0.f;               // carried state = kP * c  (folds the EC multiply)
    const int wrow = xcol * S + 8 * w + 2 * q + (col >> 3);   // loop-invariant write addr
    const f32x4 z4 = {0.f, 0.f, 0.f, 0.f};

    // x-pipeline: accx* = x-contribution for step t (ready); bxn = B-frag for step t+1
    f32x4 accx0, accx1;
    half8 bxn;
    {
        half8 bx0 = *(const half8*)&xbuf[xcol * XS + 0];
        accx0 = __builtin_amdgcn_mfma_f32_16x16x32_f16(aw[0][2], bx0, z4, 0, 0, 0);
        accx1 = __builtin_amdgcn_mfma_f32_16x16x32_f16(aw[1][2], bx0, z4, 0, 0, 0);
        bxn = *(const half8*)&xbuf[xcol * XS + 8];
    }

    #pragma unroll 4
    for (int t = 0; t < TT; ++t) {
        const int rb = t & 1, wb = rb ^ 1;
        const _Float16* sr = &st[rb][0];

        // ---- critical reads first (in-order LDS returns: bh0 arrives first) ----
        half8 bh0 = *(const half8*)&sr[xcol * S +      8 * q];   // k 0..31
        half8 bh1 = *(const half8*)&sr[xcol * S + 32 + 8 * q];   // k 32..63

        // ---- x-MFMAs for t+1: operands in regs -> issue inside read latency ----
        f32x4 axn0 = __builtin_amdgcn_mfma_f32_16x16x32_f16(aw[0][2], bxn, z4, 0, 0, 0);
        f32x4 axn1 = __builtin_amdgcn_mfma_f32_16x16x32_f16(aw[1][2], bxn, z4, 0, 0, 0);

        bxn = *(const half8*)&xbuf[xcol * XS + (t + 2) * 8];     // prefetch (pad-safe)

        // ---- h-MFMAs: 4 INDEPENDENT ops, depth-1 chain (halves summed in VALU) ----
        // Bit-identical to chained: ((accx+P0)+P1) == ((accx+P0)+(P1+0))
        f32x4 a0 = __builtin_amdgcn_mfma_f32_16x16x32_f16(aw[0][0], bh0, accx0, 0, 0, 0);
        f32x4 b0t = __builtin_amdgcn_mfma_f32_16x16x32_f16(aw[0][1], bh1, z4,   0, 0, 0);
        f32x4 a1 = __builtin_amdgcn_mfma_f32_16x16x32_f16(aw[1][0], bh0, accx1, 0, 0, 0);
        f32x4 b1t = __builtin_amdgcn_mfma_f32_16x16x32_f16(aw[1][1], bh1, z4,   0, 0, 0);

        // ---- select own tile (cols>=8 hold batch col-8 locally: no DPP) + sum halves ----
        const float gi = (lo ? a0[0] : a1[0]) + (lo ? b0t[0] : b1t[0]);  // kN-scaled
        const float gf = (lo ? a0[1] : a1[1]) + (lo ? b0t[1] : b1t[1]);  // kN-scaled
        const float gg = (lo ? a0[2] : a1[2]) + (lo ? b0t[2] : b1t[2]);  // kP-scaled
        const float go = (lo ? a0[3] : a1[3]) + (lo ? b0t[3] : b1t[3]);  // kN-scaled

        const float EI = __builtin_amdgcn_exp2f(gi);
        const float EF = __builtin_amdgcn_exp2f(gf);
        const float EG = __builtin_amdgcn_exp2f(gg);
        const float rF = __builtin_amdgcn_rcpf(1.f + EF);
        const float r1 = __builtin_amdgcn_rcpf((1.f + EI) * (EG + 1.f));
        const float Y  = (kP * (EG - 1.f)) * r1;      // kP folded off-chain
        cs2 = cs2 * rF + Y;                           // cs2 == kP * c
        const float EO = __builtin_amdgcn_exp2f(go);
        const float EC = __builtin_amdgcn_exp2f(cs2);
        const float r2 = __builtin_amdgcn_rcpf((1.f + EO) * (EC + 1.f));
        const float hn = (EC - 1.f) * r2;

        st[wb][wrow] = (_Float16)hn;    // bank-bijective across the wave: conflict-free
        __syncthreads();

        accx0 = axn0; accx1 = axn1;
    }

    // ---- FC epilogue: final h in st[0] (TT even) ----
    if (tid < MB * 4) {
        const int b = tid >> 2, o = tid & 3;
        float s = b_fc[o];
        const float* wf = W_fc + o * HH;
        #pragma unroll
        for (int k = 0; k < HH; ++k)
            s = fmaf((float)st[0][b * S + k], wf[k], s);
        out[(size_t)(b0 + b) * 4 + o] = s;
    }
}

extern "C" void kernel_launch(void* const* d_in, const int* in_sizes, int n_in,
                              void* d_out, int out_size, void* d_ws, size_t ws_size,
                              hipStream_t stream) {
    const float* x    = (const float*)d_in[0];
    const float* W_ih = (const float*)d_in[1];
    const float* W_hh = (const float*)d_in[2];
    const float* b_ih = (const float*)d_in[3];
    const float* b_hh = (const float*)d_in[4];
    const float* W_fc = (const float*)d_in[5];
    const float* b_fc = (const float*)d_in[6];
    float* out = (float*)d_out;
    lstm_v19<<<2048 / MB, 512, 0, stream>>>(x, W_ih, W_hh, b_ih, b_hh, W_fc, b_fc, out);
}

// Round 9
// 200.339 us; speedup vs baseline: 1.1251x; 1.0706x over previous
//
#include <hip/hip_runtime.h>

typedef _Float16 half8 __attribute__((ext_vector_type(8)));
typedef _Float16 half4 __attribute__((ext_vector_type(4)));
typedef float f32x4 __attribute__((ext_vector_type(4)));

#define TT 512
#define HH 64
#define MB 8      // real batches per block -> 256 blocks; cols 8..15 are broadcast dups
#define S  88     // state row stride (halfs): h-writes bank-bijective, reads at BW floor
#define XS 4112   // xbuf per-batch stride (halfs): 514*8 -> pad absorbs t+2 prefetch

__global__ __launch_bounds__(512, 1)
void lstm_v20(const float* __restrict__ x,
              const float* __restrict__ W_ih,
              const float* __restrict__ W_hh,
              const float* __restrict__ b_ih,
              const float* __restrict__ b_hh,
              const float* __restrict__ W_fc,
              const float* __restrict__ b_fc,
              float* __restrict__ out)
{
    __shared__ __align__(16) _Float16 st[2][8 * S];      // 2816 B: h state, dbuf
    __shared__ __align__(16) _Float16 xbuf[MB * XS];     // 65792 B: pre-packed x B-frags

    const int tid = threadIdx.x;
    const int w   = tid >> 6;      // wave 0..7
    const int l   = tid & 63;
    const int q   = l >> 4;
    const int col = l & 15;
    const int b0  = blockIdx.x * MB;
    const int xcol = col & 7;      // cols 8..15 broadcast a real batch
    const bool lo = (col < 8);

    const float kN = -1.4426950408889634f;   // -log2(e)
    const float kP =  2.8853900817779268f;   // +2*log2(e)

    // ---- persistent A fragments (weights), 2 tiles per wave ----
    // tile p of wave w covers gate-rows r(m) = 64*(m&3) + 8w + 2*(m>>2) + p
    // => lane (q,col) reg j = gate j of unit u = 8w + 2q + p  (batch col&7)
    //    C is column-identical across col-halves (B cols 8..15 broadcast), so
    //    lane col>=8 already holds tile p=1's gates for batch col-8 locally:
    //    select is 4 cndmask, NO cross-lane (v19-verified correct).
    // Weights PRESCALED by the sigmoid/tanh exp2 constants (f32 mul BEFORE f16
    // convert: same single rounding as unscaled).
    half8 aw[2][3];
    #pragma unroll
    for (int p = 0; p < 2; ++p) {
        const int r = 64 * (col & 3) + 8 * w + 2 * (col >> 2) + p;
        const float scale = ((col & 3) == 2) ? kP : kN;   // gate g -> kP, i/f/o -> kN
        #pragma unroll
        for (int c = 0; c < 2; ++c) {
            const float* src = W_hh + r * HH + 32 * c + 8 * q;
            half8 v;
            #pragma unroll
            for (int j = 0; j < 8; ++j) v[j] = (_Float16)(src[j] * scale);
            aw[p][c] = v;
        }
        half8 v = {};
        if (q == 0) {   // k=64..67 -> W_ih, k=68 -> bias (B supplies 1.0 at k=68)
            #pragma unroll
            for (int j = 0; j < 4; ++j) v[j] = (_Float16)(W_ih[r * 4 + j] * scale);
            v[4] = (_Float16)((b_ih[r] + b_hh[r]) * scale);
        }
        aw[p][2] = v;
    }

    // ---- pre-stage x as ready-to-use B-frags: {x0,x1,x2,x3,1,0,0,0} per (b,t) ----
    #pragma unroll
    for (int it = 0; it < (MB * TT) / 512; ++it) {
        const int task = tid + it * 512;
        const int b = task >> 9, t = task & 511;
        float4 v = *(const float4*)(x + ((size_t)(b0 + b) * TT + t) * 4);
        half8 hx;
        hx[0] = (_Float16)v.x; hx[1] = (_Float16)v.y;
        hx[2] = (_Float16)v.z; hx[3] = (_Float16)v.w;
        hx[4] = (_Float16)1.0f; hx[5] = (_Float16)0.f;
        hx[6] = (_Float16)0.f;  hx[7] = (_Float16)0.f;
        *(half8*)&xbuf[b * XS + t * 8] = hx;
    }

    // ---- zero h state (both buffers, all 8 rows) ----
    for (int i = tid; i < 2 * 8 * S; i += 512) (&st[0][0])[i] = (_Float16)0.f;
    __syncthreads();

    float cs2 = 0.f;               // carried state = kP * c  (folds the EC multiply)
    const int wrow = xcol * S + 8 * w + 2 * q + (col >> 3);   // loop-invariant write addr
    const f32x4 z4 = {0.f, 0.f, 0.f, 0.f};

    // x-pipeline: accx* = x-contribution for step t (ready); bxn = B-frag for step t+1
    f32x4 accx0, accx1;
    half8 bxn;
    {
        half8 bx0 = *(const half8*)&xbuf[xcol * XS + 0];
        accx0 = __builtin_amdgcn_mfma_f32_16x16x32_f16(aw[0][2], bx0, z4, 0, 0, 0);
        accx1 = __builtin_amdgcn_mfma_f32_16x16x32_f16(aw[1][2], bx0, z4, 0, 0, 0);
        bxn = *(const half8*)&xbuf[xcol * XS + 8];
    }

    #pragma unroll 4
    for (int t = 0; t < TT; ++t) {
        const int rb = t & 1, wb = rb ^ 1;
        const _Float16* sr = &st[rb][0];

        // ---- critical reads first ----
        half8 bh0 = *(const half8*)&sr[xcol * S +      8 * q];   // k 0..31
        half8 bh1 = *(const half8*)&sr[xcol * S + 32 + 8 * q];   // k 32..63

        // ---- x-MFMAs for t+1: operands in regs -> issue inside read latency ----
        f32x4 axn0 = __builtin_amdgcn_mfma_f32_16x16x32_f16(aw[0][2], bxn, z4, 0, 0, 0);
        f32x4 axn1 = __builtin_amdgcn_mfma_f32_16x16x32_f16(aw[1][2], bxn, z4, 0, 0, 0);

        bxn = *(const half8*)&xbuf[xcol * XS + (t + 2) * 8];     // prefetch (pad-safe)

        // ---- h-MFMAs: chained (issue-minimal; latency hidden by partner wave) ----
        f32x4 a0 = __builtin_amdgcn_mfma_f32_16x16x32_f16(aw[0][0], bh0, accx0, 0, 0, 0);
        f32x4 a1 = __builtin_amdgcn_mfma_f32_16x16x32_f16(aw[1][0], bh0, accx1, 0, 0, 0);
        a0 = __builtin_amdgcn_mfma_f32_16x16x32_f16(aw[0][1], bh1, a0, 0, 0, 0);
        a1 = __builtin_amdgcn_mfma_f32_16x16x32_f16(aw[1][1], bh1, a1, 0, 0, 0);

        // ---- select own tile (4 cndmask; cols>=8 hold batch col-8 locally) ----
        const float gi = lo ? a0[0] : a1[0];   // prescaled by kN
        const float gf = lo ? a0[1] : a1[1];   // prescaled by kN
        const float gg = lo ? a0[2] : a1[2];   // prescaled by kP
        const float go = lo ? a0[3] : a1[3];   // prescaled by kN

        const float EI = __builtin_amdgcn_exp2f(gi);
        const float EF = __builtin_amdgcn_exp2f(gf);
        const float EG = __builtin_amdgcn_exp2f(gg);
        const float rF = __builtin_amdgcn_rcpf(1.f + EF);
        const float r1 = __builtin_amdgcn_rcpf((1.f + EI) * (EG + 1.f));
        const float Yn = __builtin_fmaf(kP, EG, -kP);  // kP*(EG-1) as one fma
        const float Y  = Yn * r1;
        cs2 = cs2 * rF + Y;                            // cs2 == kP * c
        const float EO = __builtin_amdgcn_exp2f(go);
        const float EC = __builtin_amdgcn_exp2f(cs2);
        const float r2 = __builtin_amdgcn_rcpf((1.f + EO) * (EC + 1.f));
        const float hn = (EC - 1.f) * r2;

        st[wb][wrow] = (_Float16)hn;    // bank-bijective across the wave: conflict-free
        __syncthreads();

        accx0 = axn0; accx1 = axn1;
    }

    // ---- FC epilogue: final h in st[0] (TT even) ----
    if (tid < MB * 4) {
        const int b = tid >> 2, o = tid & 3;
        float s = b_fc[o];
        const float* wf = W_fc + o * HH;
        #pragma unroll
        for (int k = 0; k < HH; ++k)
            s = fmaf((float)st[0][b * S + k], wf[k], s);
        out[(size_t)(b0 + b) * 4 + o] = s;
    }
}

extern "C" void kernel_launch(void* const* d_in, const int* in_sizes, int n_in,
                              void* d_out, int out_size, void* d_ws, size_t ws_size,
                              hipStream_t stream) {
    const float* x    = (const float*)d_in[0];
    const float* W_ih = (const float*)d_in[1];
    const float* W_hh = (const float*)d_in[2];
    const float* b_ih = (const float*)d_in[3];
    const float* b_hh = (const float*)d_in[4];
    const float* W_fc = (const float*)d_in[5];
    const float* b_fc = (const float*)d_in[6];
    float* out = (float*)d_out;
    lstm_v20<<<2048 / MB, 512, 0, stream>>>(x, W_ih, W_hh, b_ih, b_hh, W_fc, b_fc, out);
}

// Round 10
// 199.717 us; speedup vs baseline: 1.1286x; 1.0031x over previous
//
#include <hip/hip_runtime.h>

typedef _Float16 half8 __attribute__((ext_vector_type(8)));
typedef _Float16 half4 __attribute__((ext_vector_type(4)));
typedef float f32x4 __attribute__((ext_vector_type(4)));

#define TT 512
#define HH 64
#define MB 8      // real batches per block -> 256 blocks; cols 8..15 select tile p=1
#define S  88     // state row stride (halfs): h-writes bank-bijective, reads at BW floor
#define XS 4112   // xbuf per-batch stride (halfs): 514*8 -> pad absorbs t+2/t+3 prefetch

#define MFMA16(A, B, C) __builtin_amdgcn_mfma_f32_16x16x32_f16((A), (B), (C), 0, 0, 0)

// one LSTM cell update; gates prescaled (i,f,o by -log2e; g by 2log2e); cs2 == kP*c
__device__ __forceinline__ float lstm_update(float gi, float gf, float gg, float go,
                                             float& cs2) {
    const float kP = 2.8853900817779268f;        // 2*log2(e)
    const float EI = __builtin_amdgcn_exp2f(gi); // e^-i
    const float EF = __builtin_amdgcn_exp2f(gf); // e^-f
    const float EG = __builtin_amdgcn_exp2f(gg); // e^{2g}
    const float EO = __builtin_amdgcn_exp2f(go); // e^-o
    // single-rcp fold: c' = c*sig(f) + sig(i)*tanh(g)
    //   = [cs2*m1 + kP*(EG-1)*EF1] / (EF1*m1),  m1=(1+EI)(EG+1), EF1=1+EF
    const float EF1 = 1.f + EF;
    const float m1  = (1.f + EI) * (EG + 1.f);
    const float rD  = __builtin_amdgcn_rcpf(EF1 * m1);
    const float Yn  = __builtin_fmaf(kP, EG, -kP);          // kP*(EG-1)
    const float num = __builtin_fmaf(cs2, m1, Yn * EF1);
    cs2 = num * rD;                                          // cs2' == kP*c'
    const float EC = __builtin_amdgcn_exp2f(cs2);            // e^{2c'}
    const float r2 = __builtin_amdgcn_rcpf((1.f + EO) * (EC + 1.f));
    return (EC - 1.f) * r2;                                  // sig(o)*tanh(c')
}

__global__ __launch_bounds__(512, 1)
void lstm_v21(const float* __restrict__ x,
              const float* __restrict__ W_ih,
              const float* __restrict__ W_hh,
              const float* __restrict__ b_ih,
              const float* __restrict__ b_hh,
              const float* __restrict__ W_fc,
              const float* __restrict__ b_fc,
              float* __restrict__ out)
{
    __shared__ __align__(16) _Float16 st[2][8 * S];      // 2816 B: h state, dbuf
    __shared__ __align__(16) _Float16 xbuf[MB * XS];     // 65792 B: pre-packed x B-frags

    const int tid = threadIdx.x;
    const int w   = tid >> 6;      // wave 0..7
    const int l   = tid & 63;
    const int q   = l >> 4;
    const int col = l & 15;
    const int b0  = blockIdx.x * MB;
    const int xcol = col & 7;      // cols 8..15 share a real batch's B-column
    const bool lo = (col < 8);

    const float kN = -1.4426950408889634f;   // -log2(e)
    const float kP =  2.8853900817779268f;   // +2*log2(e)

    // ---- persistent A fragments (weights), 2 tiles per wave ----
    // tile p of wave w covers gate-rows r(m) = 64*(m&3) + 8w + 2*(m>>2) + p
    // => lane (q,col) reg j = gate j of unit u = 8w + 2q + p  (batch col&7)
    //    C is column-identical across col-halves (B cols 8..15 broadcast), so
    //    lane col>=8 holds tile p=1's gates for batch col-8 locally: select is
    //    4 cndmask, no cross-lane (v19/v20-verified).
    // Weights PRESCALED by exp2 constants (f32 mul BEFORE f16 cvt: single rounding).
    half8 aw[2][3];
    #pragma unroll
    for (int p = 0; p < 2; ++p) {
        const int r = 64 * (col & 3) + 8 * w + 2 * (col >> 2) + p;
        const float scale = ((col & 3) == 2) ? kP : kN;   // gate g -> kP, i/f/o -> kN
        #pragma unroll
        for (int c = 0; c < 2; ++c) {
            const float* src = W_hh + r * HH + 32 * c + 8 * q;
            half8 v;
            #pragma unroll
            for (int j = 0; j < 8; ++j) v[j] = (_Float16)(src[j] * scale);
            aw[p][c] = v;
        }
        half8 v = {};
        if (q == 0) {   // k=64..67 -> W_ih, k=68 -> bias (B supplies 1.0 at k=68)
            #pragma unroll
            for (int j = 0; j < 4; ++j) v[j] = (_Float16)(W_ih[r * 4 + j] * scale);
            v[4] = (_Float16)((b_ih[r] + b_hh[r]) * scale);
        }
        aw[p][2] = v;
    }

    // ---- pre-stage x as ready-to-use B-frags: {x0,x1,x2,x3,1,0,0,0} per (b,t) ----
    #pragma unroll
    for (int it = 0; it < (MB * TT) / 512; ++it) {
        const int task = tid + it * 512;
        const int b = task >> 9, t = task & 511;
        float4 v = *(const float4*)(x + ((size_t)(b0 + b) * TT + t) * 4);
        half8 hx;
        hx[0] = (_Float16)v.x; hx[1] = (_Float16)v.y;
        hx[2] = (_Float16)v.z; hx[3] = (_Float16)v.w;
        hx[4] = (_Float16)1.0f; hx[5] = (_Float16)0.f;
        hx[6] = (_Float16)0.f;  hx[7] = (_Float16)0.f;
        *(half8*)&xbuf[b * XS + t * 8] = hx;
    }

    // ---- zero h state (both buffers, all 8 rows) ----
    for (int i = tid; i < 2 * 8 * S; i += 512) (&st[0][0])[i] = (_Float16)0.f;
    __syncthreads();

    float cs2 = 0.f;               // carried state = kP * c
    const f32x4 z4 = {0.f, 0.f, 0.f, 0.f};

    // loop-invariant addresses (ping-pong buffers are static per half-body)
    const _Float16* sr0 = &st[0][xcol * S + 8 * q];   // read base, even steps
    const _Float16* sr1 = &st[1][xcol * S + 8 * q];   // read base, odd steps
    _Float16* pw0 = &st[1][xcol * S + 8 * w + 2 * q + (col >> 3)];  // write, even
    _Float16* pw1 = &st[0][xcol * S + 8 * w + 2 * q + (col >> 3)];  // write, odd
    const _Float16* xp = &xbuf[xcol * XS];            // advanced 16 halfs per 2 steps

    // x-pipeline: accxA* = x-contribution for step t (ready); bxA = frag for t+1
    f32x4 accxA0, accxA1, accxB0, accxB1;
    half8 bxA, bxB;
    {
        half8 bx0 = *(const half8*)(xp + 0);
        accxA0 = MFMA16(aw[0][2], bx0, z4);
        accxA1 = MFMA16(aw[1][2], bx0, z4);
        bxA = *(const half8*)(xp + 8);
    }

    #pragma unroll 2
    for (int it = 0; it < TT / 2; ++it) {
        // ================= even step (t = 2it): read st[0], write st[1] =========
        {
            half8 bh0 = *(const half8*)(sr0);        // k 0..31
            half8 bh1 = *(const half8*)(sr0 + 32);   // k 32..63

            // x-MFMAs for t+1 (operands ready) inside the h-read latency window
            accxB0 = MFMA16(aw[0][2], bxA, z4);
            accxB1 = MFMA16(aw[1][2], bxA, z4);
            bxB = *(const half8*)(xp + 16);          // frag for t+2 (pad-safe)

            // h-MFMAs: chained (issue-minimal; latency hidden by partner wave)
            f32x4 a0 = MFMA16(aw[0][0], bh0, accxA0);
            f32x4 a1 = MFMA16(aw[1][0], bh0, accxA1);
            a0 = MFMA16(aw[0][1], bh1, a0);
            a1 = MFMA16(aw[1][1], bh1, a1);

            const float gi = lo ? a0[0] : a1[0];
            const float gf = lo ? a0[1] : a1[1];
            const float gg = lo ? a0[2] : a1[2];
            const float go = lo ? a0[3] : a1[3];
            const float hn = lstm_update(gi, gf, gg, go, cs2);

            *pw0 = (_Float16)hn;                     // bank-bijective: conflict-free
            __syncthreads();
        }
        // ================= odd step (t = 2it+1): read st[1], write st[0] ========
        {
            half8 bh0 = *(const half8*)(sr1);
            half8 bh1 = *(const half8*)(sr1 + 32);

            accxA0 = MFMA16(aw[0][2], bxB, z4);
            accxA1 = MFMA16(aw[1][2], bxB, z4);
            bxA = *(const half8*)(xp + 24);          // frag for t+3 (pad-safe)

            f32x4 a0 = MFMA16(aw[0][0], bh0, accxB0);
            f32x4 a1 = MFMA16(aw[1][0], bh0, accxB1);
            a0 = MFMA16(aw[0][1], bh1, a0);
            a1 = MFMA16(aw[1][1], bh1, a1);

            const float gi = lo ? a0[0] : a1[0];
            const float gf = lo ? a0[1] : a1[1];
            const float gg = lo ? a0[2] : a1[2];
            const float go = lo ? a0[3] : a1[3];
            const float hn = lstm_update(gi, gf, gg, go, cs2);

            *pw1 = (_Float16)hn;
            __syncthreads();
        }
        xp += 16;
    }

    // ---- FC epilogue: final h in st[0] (TT even) ----
    if (tid < MB * 4) {
        const int b = tid >> 2, o = tid & 3;
        float s = b_fc[o];
        const float* wf = W_fc + o * HH;
        #pragma unroll
        for (int k = 0; k < HH; ++k)
            s = fmaf((float)st[0][b * S + k], wf[k], s);
        out[(size_t)(b0 + b) * 4 + o] = s;
    }
}

extern "C" void kernel_launch(void* const* d_in, const int* in_sizes, int n_in,
                              void* d_out, int out_size, void* d_ws, size_t ws_size,
                              hipStream_t stream) {
    const float* x    = (const float*)d_in[0];
    const float* W_ih = (const float*)d_in[1];
    const float* W_hh = (const float*)d_in[2];
    const float* b_ih = (const float*)d_in[3];
    const float* b_hh = (const float*)d_in[4];
    const float* W_fc = (const float*)d_in[5];
    const float* b_fc = (const float*)d_in[6];
    float* out = (float*)d_out;
    lstm_v21<<<2048 / MB, 512, 0, stream>>>(x, W_ih, W_hh, b_ih, b_hh, W_fc, b_fc, out);
}